// Round 10
// baseline (764.402 us; speedup 1.0000x reference)
//
#include <hip/hip_runtime.h>

typedef _Float16 f16x8 __attribute__((ext_vector_type(8)));
typedef float f32x4 __attribute__((ext_vector_type(4)));
typedef unsigned short u16x8 __attribute__((ext_vector_type(8)));

constexpr int T = 8192, H = 2048, HS = 4096, P = 1024, E = 8;
constexpr int RBLK = 512;   // router blocks = T/16

// ---- d_out layout (floats): final [T*H] | router_logits [T*E] | aux_loss [1]
constexpr size_t LOGITS_OFF = (size_t)T * H;
constexpr size_t AUX_OFF    = LOGITS_OFF + (size_t)T * E;

// ---- workspace layout (bytes) — aliased buffers keep total ~225 MiB
// BIG0: x16 [T*H f16]   (dead after G1)  -> act  [T*2*P f16] (written G3)
// BIG1: c1  [T*HS f16]  (dead after G2)  -> slot [T*2*H f16] (written G4)
constexpr size_t OFF_SGW  = 0;
constexpr size_t OFF_SDW  = OFF_SGW  + (size_t)HS * H * 2;
constexpr size_t OFF_GW   = OFF_SDW  + (size_t)H * HS * 2;
constexpr size_t OFF_DW   = OFF_GW   + (size_t)E * P * H * 2;
constexpr size_t OFF_BIG0 = OFF_DW   + (size_t)E * H * P * 2;
constexpr size_t OFF_BIG1 = OFF_BIG0 + (size_t)T * H * 2;      // == T*2*P*2
constexpr size_t OFF_H1   = OFF_BIG1 + (size_t)T * HS * 2;     // == T*2*H*2
constexpr size_t OFF_GALL = OFF_H1   + (size_t)T * H * 2;
constexpr size_t OFF_IMP  = OFF_GALL + (size_t)T * E * 4;
constexpr size_t OFF_OFFS = OFF_IMP  + 256;
constexpr size_t OFF_SEL  = OFF_OFFS + 256;
constexpr size_t OFF_SELW = OFF_SEL  + (size_t)T * 2 * 4;
constexpr size_t OFF_POS  = OFF_SELW + (size_t)T * 2 * 4;
constexpr size_t OFF_AID  = OFF_POS  + (size_t)T * 2 * 4;
constexpr size_t OFF_TOK  = OFF_AID  + (size_t)T * 2 * 4;
constexpr size_t OFF_WOF  = OFF_TOK  + (size_t)T * 2 * 4;
constexpr size_t OFF_BCNT = OFF_WOF  + (size_t)T * 2 * 4;      // [RBLK][E] int
constexpr size_t OFF_BBAS = OFF_BCNT + (size_t)RBLK * E * 4;   // [RBLK][E] int

__device__ __forceinline__ unsigned short f2h(float f) {
  return __builtin_bit_cast(unsigned short, (_Float16)f);
}
__device__ __forceinline__ float h2f(unsigned short u) {
  return (float)__builtin_bit_cast(_Float16, u);
}
__device__ __forceinline__ void gload16(const void* g, void* l) {
  __builtin_amdgcn_global_load_lds((__attribute__((address_space(1))) void*)g,
                                   (__attribute__((address_space(3))) void*)l, 16, 0, 0);
}

// -------------------- fused weight convert (+ zero of imp) --------------------
__global__ void cvt4_kernel(const float* __restrict__ s0, const float* __restrict__ s1,
                            const float* __restrict__ s2, const float* __restrict__ s3,
                            unsigned short* __restrict__ d, float* __restrict__ imp) {
  if (blockIdx.x == 0 && threadIdx.x < E) imp[threadIdx.x] = 0.f;
  const int i = blockIdx.x * 256 + threadIdx.x;   // float4 index, [0, 12M)
  constexpr int N0 = (HS * H) / 4;
  constexpr int N1 = N0 + (H * HS) / 4;
  constexpr int N2 = N1 + (E * P * H) / 4;
  float4 v;
  if (i < N0)      v = ((const float4*)s0)[i];
  else if (i < N1) v = ((const float4*)s1)[i - N0];
  else if (i < N2) v = ((const float4*)s2)[i - N1];
  else             v = ((const float4*)s3)[i - N2];
  ushort4 o;
  o.x = f2h(v.x); o.y = f2h(v.y); o.z = f2h(v.z); o.w = f2h(v.w);
  ((ushort4*)d)[i] = o;
}

// -------------------- router (rw staged in LDS; emits x16, ranks, block counts) ----
// Deterministic token-ordered ranks -> sorted-by-token expert assignment lists.
__global__ void router_kernel(const float* __restrict__ x, const float* __restrict__ rw,
                              float* __restrict__ logits, float* __restrict__ impg,
                              int* __restrict__ sel, float* __restrict__ selw,
                              int* __restrict__ posA, int* __restrict__ block_cnt,
                              unsigned short* __restrict__ x16) {
  __shared__ float sRW[E * H];        // 64 KiB: whole router weight staged once
  __shared__ float sImp[E];
  __shared__ int sE[16][2];
  __shared__ int sRank[16][2];
  __shared__ int sBC[E];
  const int tid = threadIdx.x, lane = tid & 63, wid = tid >> 6;
  if (tid < E) sImp[tid] = 0.f;
#pragma unroll
  for (int i = 0; i < (E * H / 4) / 256; ++i)
    ((float4*)sRW)[i * 256 + tid] = ((const float4*)rw)[i * 256 + tid];
  __syncthreads();

  for (int i = 0; i < 4; ++i) {
    const int ti = wid * 4 + i;
    const int t = blockIdx.x * 16 + ti;
    float p[E];
#pragma unroll
    for (int e = 0; e < E; ++e) p[e] = 0.f;
    const float4* xr = (const float4*)(x + (size_t)t * H);
#pragma unroll
    for (int q = 0; q < 8; ++q) {
      float4 xv = xr[q * 64 + lane];
      ushort4 xo;
      xo.x = f2h(xv.x); xo.y = f2h(xv.y); xo.z = f2h(xv.z); xo.w = f2h(xv.w);
      ((ushort4*)(x16 + (size_t)t * H))[q * 64 + lane] = xo;
#pragma unroll
      for (int e = 0; e < E; ++e) {
        float4 wv = ((const float4*)sRW)[e * 512 + q * 64 + lane];
        p[e] += xv.x * wv.x + xv.y * wv.y + xv.z * wv.z + xv.w * wv.w;
      }
    }
#pragma unroll
    for (int e = 0; e < E; ++e)
#pragma unroll
      for (int o = 32; o; o >>= 1) p[e] += __shfl_xor(p[e], o);

    if (lane == 0) {
      float mx = p[0];
#pragma unroll
      for (int e = 1; e < E; ++e) mx = fmaxf(mx, p[e]);
      float pe[E], s = 0.f;
#pragma unroll
      for (int e = 0; e < E; ++e) { pe[e] = expf(p[e] - mx); s += pe[e]; }
      float inv = 1.f / s;
      int i1 = 0; float b1 = pe[0];
#pragma unroll
      for (int e = 1; e < E; ++e) if (pe[e] > b1) { b1 = pe[e]; i1 = e; }
      int i2 = -1; float b2 = -1.f;
#pragma unroll
      for (int e = 0; e < E; ++e) if (e != i1 && pe[e] > b2) { b2 = pe[e]; i2 = e; }
#pragma unroll
      for (int e = 0; e < E; ++e) logits[(size_t)t * E + e] = p[e];
#pragma unroll
      for (int e = 0; e < E; ++e) atomicAdd(&sImp[e], pe[e] * inv);
      sel[t * 2] = i1; sel[t * 2 + 1] = i2;
      selw[t * 2] = b1 * inv; selw[t * 2 + 1] = b2 * inv;
      sE[ti][0] = i1; sE[ti][1] = i2;
    }
  }
  __syncthreads();
  // token-ordered within-block ranks (deterministic counting sort)
  if (tid == 0) {
    int bc[E];
#pragma unroll
    for (int e = 0; e < E; ++e) bc[e] = 0;
    for (int ti = 0; ti < 16; ++ti) {
      sRank[ti][0] = bc[sE[ti][0]]++;
      sRank[ti][1] = bc[sE[ti][1]]++;
    }
#pragma unroll
    for (int e = 0; e < E; ++e) sBC[e] = bc[e];
  }
  __syncthreads();
  if (tid < E) {
    block_cnt[blockIdx.x * E + tid] = sBC[tid];
    atomicAdd(&impg[tid], sImp[tid]);
  }
  if (tid < 32) {
    const int ti = tid >> 1, k = tid & 1;
    posA[(blockIdx.x * 16 + ti) * 2 + k] = sRank[ti][k];
  }
}

// -------------------- scan: per-expert prefix over block counts + offs + aux ----
__global__ void scan_kernel(const int* __restrict__ block_cnt, const float* __restrict__ imp,
                            int* __restrict__ block_base, int* __restrict__ offs,
                            float* __restrict__ aux_out) {
  const int lane = threadIdx.x & 63, w = threadIdx.x >> 6;   // wave w -> expert w
  __shared__ int sTot[E];
  int carry = 0;
  for (int c = 0; c < RBLK / 64; ++c) {
    const int b = c * 64 + lane;
    const int v = block_cnt[b * E + w];
    int xv = v;
#pragma unroll
    for (int off = 1; off < 64; off <<= 1) {
      int n = __shfl_up(xv, off);
      if (lane >= off) xv += n;
    }
    block_base[b * E + w] = carry + xv - v;   // exclusive prefix
    carry += __shfl(xv, 63);
  }
  if (lane == 0) sTot[w] = carry;
  __syncthreads();
  if (threadIdx.x == 0) {
    int pre[E + 1];
    pre[0] = 0;
#pragma unroll
    for (int e = 0; e < E; ++e) pre[e + 1] = pre[e] + sTot[e];
#pragma unroll
    for (int e = 0; e <= E; ++e) offs[e] = pre[e];
    float simp = 0.f, sld = (float)pre[E];
#pragma unroll
    for (int e = 0; e < E; ++e) simp += imp[e];
    float aux = 0.f;
#pragma unroll
    for (int e = 0; e < E; ++e)
      aux += (imp[e] / (simp + 1e-9f)) * ((float)sTot[e] / (sld + 1e-9f));
    aux_out[0] = (float)E * aux;
  }
}

// -------------------- fill: assignment-id maps (sorted order) --------------------
__global__ void fill_kernel(const int* __restrict__ sel, const float* __restrict__ selw,
                            const int* __restrict__ posA, const int* __restrict__ block_base,
                            const int* __restrict__ offs,
                            int* __restrict__ tok_of, float* __restrict__ w_of,
                            int* __restrict__ aid_of) {
  const int idx = blockIdx.x * 256 + threadIdx.x;  // 0 .. T*2
  if (idx >= T * 2) return;
  const int t = idx >> 1;
  const int e = sel[idx];
  const int aid = offs[e] + block_base[(t >> 4) * E + e] + posA[idx];
  tok_of[aid] = t;
  w_of[aid] = selw[idx];
  aid_of[idx] = aid;
}

// -------------------- g kernel: g_all[t,e] = sigmoid(h1 . pg_w[e]) --------------------
__global__ void g_kernel(const unsigned short* __restrict__ h1, const float* __restrict__ pgw,
                         float* __restrict__ g_all) {
  const int lane = threadIdx.x & 63, wid = threadIdx.x >> 6;
  const int t = blockIdx.x * 4 + wid;
  float p[E];
#pragma unroll
  for (int e = 0; e < E; ++e) p[e] = 0.f;
#pragma unroll
  for (int i = 0; i < 4; ++i) {
    const int h = (i * 64 + lane) * 8;
    u16x8 hv = *(const u16x8*)(h1 + (size_t)t * H + h);
    float hf[8];
#pragma unroll
    for (int j = 0; j < 8; ++j) hf[j] = h2f(hv[j]);
#pragma unroll
    for (int e = 0; e < E; ++e) {
      const float4* wp = (const float4*)(pgw + (size_t)e * H + h);
      float4 w0 = wp[0], w1 = wp[1];
      p[e] += hf[0] * w0.x + hf[1] * w0.y + hf[2] * w0.z + hf[3] * w0.w +
              hf[4] * w1.x + hf[5] * w1.y + hf[6] * w1.z + hf[7] * w1.w;
    }
  }
#pragma unroll
  for (int e = 0; e < E; ++e)
#pragma unroll
    for (int o = 32; o; o >>= 1) p[e] += __shfl_xor(p[e], o);
  if (lane == 0) {
#pragma unroll
    for (int e = 0; e < E; ++e) g_all[(size_t)t * E + e] = 1.f / (1.f + expf(-p[e]));
  }
}

// -------------------- the GEMM: C[M,N] = A[M,K] . B[N,K]^T (f16 in, MFMA, f16 out)
// Proven core (128x128 tile, 4 waves, BK=64, T2 swizzle, global_load_lds w=16).
// r9: XCD-slab swizzle for MODE<=1. r10: __launch_bounds__(256,4) — 64V+64A=128
// regs/wave = exactly 512/4, LDS 32KBx4=128<=160 -> 4 blocks/CU.
// MODE 0: plain rows, relu; MODE 1: plain; MODE 2: gathered rows (now SORTED),
// relu(g*v); MODE 3: rows=aid, w*v.
template <int MODE>
__global__ __launch_bounds__(256, 4) void gemm_bt(
    const unsigned short* __restrict__ A, const unsigned short* __restrict__ B,
    unsigned short* __restrict__ Cout, const int* __restrict__ tok_of,
    const float* __restrict__ g_all, const float* __restrict__ w_of,
    const int* __restrict__ offs, int N, int K) {
  __shared__ alignas(128) char sA[128 * 64 * 2];
  __shared__ alignas(128) char sB[128 * 64 * 2];
  const int tid = threadIdx.x, lane = tid & 63, wid = tid >> 6;
  const int wr = wid >> 1, wc = wid & 1;

  int bm = blockIdx.x, bn = blockIdx.y;
  int rowStart = 0, cnt = 1 << 30, e = 0;
  const unsigned short* Bp = B;
  if (MODE <= 1) {
    // XCD-slab swizzle: valid when gridDim.x == 64 (G1 & G2: T/128 = 64).
    if (gridDim.x == 64) {
      const int wg = blockIdx.y * 64 + blockIdx.x;
      const int xcd = wg & 7;
      const int idx = wg >> 3;            // 0 .. nwg/8-1
      bm = xcd * 8 + (idx & 7);           // contiguous 8-panel A-slab per XCD
      bn = idx >> 3;                      // sweep N within the slab
    }
  } else {
    e = blockIdx.z;
    rowStart = offs[e];
    cnt = offs[e + 1] - rowStart;
    if (bm * 128 >= cnt) return;   // uniform per block: barrier-safe
    Bp = B + (size_t)e * N * K;
  }

  // staging pointers: chunk ci = wid*4+it covers tile bytes [ci*1024, +1024), lane -> +lane*16
  const char* aSrc[4];
  const char* bSrc[4];
  char* dA[4];
  char* dB[4];
#pragma unroll
  for (int it = 0; it < 4; ++it) {
    const int ci = wid * 4 + it;
    const int o = ci * 1024 + lane * 16;
    const int row = o >> 7;                        // 128 B per row (BK=64 f16)
    const int cbs = (o & 127) ^ ((row & 7) << 4);  // pre-swizzled source column
    dA[it] = sA + ci * 1024;
    dB[it] = sB + ci * 1024;
    long arow;
    if (MODE <= 1) {
      arow = (long)(bm * 128 + row);
    } else if (MODE == 2) {
      int grow = bm * 128 + row;
      arow = (grow < cnt) ? (long)tok_of[rowStart + grow] : 0L;
    } else {
      int grow = bm * 128 + row;
      arow = (grow < cnt) ? (long)(rowStart + grow) : (long)rowStart;
    }
    aSrc[it] = (const char*)A + arow * (long)K * 2 + cbs;
    bSrc[it] = (const char*)Bp + (long)(bn * 128 + row) * (long)K * 2 + cbs;
  }

  f32x4 acc[4][4];
#pragma unroll
  for (int a_ = 0; a_ < 4; ++a_)
#pragma unroll
    for (int b_ = 0; b_ < 4; ++b_) acc[a_][b_] = (f32x4){0.f, 0.f, 0.f, 0.f};

  for (int k0 = 0; k0 < K; k0 += 64) {
#pragma unroll
    for (int it = 0; it < 4; ++it) {
      gload16(aSrc[it] + (size_t)k0 * 2, dA[it]);
      gload16(bSrc[it] + (size_t)k0 * 2, dB[it]);
    }
    __syncthreads();
#pragma unroll
    for (int kk = 0; kk < 2; ++kk) {
      f16x8 af[4], bfr[4];
      const int c0 = kk * 64 + (lane >> 4) * 16;
#pragma unroll
      for (int mt = 0; mt < 4; ++mt) {
        const int r = wr * 64 + mt * 16 + (lane & 15);
        af[mt] = *(const f16x8*)(sA + r * 128 + (c0 ^ ((r & 7) << 4)));
      }
#pragma unroll
      for (int nt = 0; nt < 4; ++nt) {
        const int r = wc * 64 + nt * 16 + (lane & 15);
        bfr[nt] = *(const f16x8*)(sB + r * 128 + (c0 ^ ((r & 7) << 4)));
      }
#pragma unroll
      for (int mt = 0; mt < 4; ++mt)
#pragma unroll
        for (int nt = 0; nt < 4; ++nt)
          acc[mt][nt] = __builtin_amdgcn_mfma_f32_16x16x32_f16(af[mt], bfr[nt], acc[mt][nt], 0, 0, 0);
    }
    __syncthreads();
  }

  // epilogue: C row = bm*128 + wr*64 + mt*16 + (lane>>4)*4 + j ; col = bn*128 + wc*64 + nt*16 + (lane&15)
  const int colBase = bn * 128 + wc * 64 + (lane & 15);
#pragma unroll
  for (int mt = 0; mt < 4; ++mt) {
#pragma unroll
    for (int j = 0; j < 4; ++j) {
      const int rloc = wr * 64 + mt * 16 + (lane >> 4) * 4 + j;
      const int grow = bm * 128 + rloc;
      if (MODE <= 1) {
        const size_t base = (size_t)grow * N;
#pragma unroll
        for (int nt = 0; nt < 4; ++nt) {
          float v = acc[mt][nt][j];
          if (MODE == 0) v = fmaxf(v, 0.f);
          Cout[base + colBase + nt * 16] = f2h(v);
        }
      } else if (MODE == 2) {
        if (grow < cnt) {
          const int aid = rowStart + grow;
          const float g = g_all[(size_t)tok_of[aid] * E + e];
          const size_t base = (size_t)aid * N;
#pragma unroll
          for (int nt = 0; nt < 4; ++nt) {
            float v = fmaxf(g * acc[mt][nt][j], 0.f);
            Cout[base + colBase + nt * 16] = f2h(v);
          }
        }
      } else {
        if (grow < cnt) {
          const int aid = rowStart + grow;
          const float w = w_of[aid];
          const size_t base = (size_t)aid * N;
#pragma unroll
          for (int nt = 0; nt < 4; ++nt)
            Cout[base + colBase + nt * 16] = f2h(w * acc[mt][nt][j]);
        }
      }
    }
  }
}

// -------------------- combine: final[t,:] = slot[aid0] + slot[aid1] --------------------
__global__ void combine_kernel(const unsigned short* __restrict__ slot,
                               const int* __restrict__ aid_of, float* __restrict__ out) {
  const int idx = blockIdx.x * 256 + threadIdx.x;
  const int t = idx >> 8;
  const int c8 = (idx & 255) * 8;
  const int a0 = aid_of[t * 2], a1 = aid_of[t * 2 + 1];
  u16x8 v0 = *(const u16x8*)(slot + (size_t)a0 * H + c8);
  u16x8 v1 = *(const u16x8*)(slot + (size_t)a1 * H + c8);
  float4 f0, f1;
  f0.x = h2f(v0[0]) + h2f(v1[0]); f0.y = h2f(v0[1]) + h2f(v1[1]);
  f0.z = h2f(v0[2]) + h2f(v1[2]); f0.w = h2f(v0[3]) + h2f(v1[3]);
  f1.x = h2f(v0[4]) + h2f(v1[4]); f1.y = h2f(v0[5]) + h2f(v1[5]);
  f1.z = h2f(v0[6]) + h2f(v1[6]); f1.w = h2f(v0[7]) + h2f(v1[7]);
  float4* op = (float4*)(out + (size_t)t * H + c8);
  op[0] = f0; op[1] = f1;
}

// -------------------- launch --------------------
extern "C" void kernel_launch(void* const* d_in, const int* in_sizes, int n_in,
                              void* d_out, int out_size, void* d_ws, size_t ws_size,
                              hipStream_t stream) {
  const float* x   = (const float*)d_in[0];
  const float* rw  = (const float*)d_in[1];
  const float* sgw = (const float*)d_in[2];
  const float* sdw = (const float*)d_in[3];
  const float* pgw = (const float*)d_in[4];
  const float* gw  = (const float*)d_in[5];
  const float* dw  = (const float*)d_in[6];
  float* out = (float*)d_out;
  char* wsb = (char*)d_ws;

  unsigned short* sgw16 = (unsigned short*)(wsb + OFF_SGW);
  unsigned short* sdw16 = (unsigned short*)(wsb + OFF_SDW);
  unsigned short* gw16  = (unsigned short*)(wsb + OFF_GW);
  unsigned short* dw16  = (unsigned short*)(wsb + OFF_DW);
  unsigned short* x16   = (unsigned short*)(wsb + OFF_BIG0);  // alias: act
  unsigned short* act   = (unsigned short*)(wsb + OFF_BIG0);
  unsigned short* c1    = (unsigned short*)(wsb + OFF_BIG1);  // alias: slot
  unsigned short* slot  = (unsigned short*)(wsb + OFF_BIG1);
  unsigned short* h1    = (unsigned short*)(wsb + OFF_H1);
  float* gall  = (float*)(wsb + OFF_GALL);
  float* imp   = (float*)(wsb + OFF_IMP);
  int*   offs  = (int*)(wsb + OFF_OFFS);
  int*   sel   = (int*)(wsb + OFF_SEL);
  float* selw  = (float*)(wsb + OFF_SELW);
  int*   posA  = (int*)(wsb + OFF_POS);
  int*   aidof = (int*)(wsb + OFF_AID);
  int*   tokof = (int*)(wsb + OFF_TOK);
  float* wof   = (float*)(wsb + OFF_WOF);
  int*   bcnt  = (int*)(wsb + OFF_BCNT);
  int*   bbase = (int*)(wsb + OFF_BBAS);

  // fused weight converts (+ zero imp in block 0): 12M float4 total
  cvt4_kernel<<<(HS * H + H * HS + E * P * H + E * H * P) / 4 / 256, 256, 0, stream>>>(
      sgw, sdw, gw, dw, sgw16, imp);

  // router: logits, x16, selections, token-ordered ranks, per-block counts
  router_kernel<<<RBLK, 256, 0, stream>>>(x, rw, out + LOGITS_OFF, imp, sel, selw, posA, bcnt, x16);

  // scan: per-expert exclusive prefix over block counts; offs; aux
  scan_kernel<<<1, 512, 0, stream>>>(bcnt, imp, bbase, offs, out + AUX_OFF);

  // fill: sorted assignment maps
  fill_kernel<<<(T * 2) / 256, 256, 0, stream>>>(sel, selw, posA, bbase, offs, tokof, wof, aidof);

  // G1: [T,HS] = relu(x16 . sgw^T), K=H
  gemm_bt<0><<<dim3(T / 128, HS / 128), 256, 0, stream>>>(x16, sgw16, c1, nullptr, nullptr, nullptr, nullptr, HS, H);
  // G2: h1[T,H] = c1 . sdw^T, K=HS
  gemm_bt<1><<<dim3(T / 128, H / 128), 256, 0, stream>>>(c1, sdw16, h1, nullptr, nullptr, nullptr, nullptr, H, HS);
  // g
  g_kernel<<<T / 4, 256, 0, stream>>>(h1, pgw, gall);
  // G3: act[aid,P] = relu(g * (h1_gathered . gw[e]^T)), K=H  (gather now token-sorted)
  gemm_bt<2><<<dim3(T / 128, P / 128, E), 256, 0, stream>>>(h1, gw16, act, tokof, gall, nullptr, offs, P, H);
  // G4: slot[aid,H] = w * (act . dw[e]^T), K=P
  gemm_bt<3><<<dim3(T / 128, H / 128, E), 256, 0, stream>>>(act, dw16, slot, tokof, nullptr, wof, offs, H, P);

  combine_kernel<<<(T * 256) / 256, 256, 0, stream>>>(slot, aidof, out);
}

// Round 11
// 655.367 us; speedup vs baseline: 1.1664x; 1.1664x over previous
//
#include <hip/hip_runtime.h>

typedef _Float16 f16x8 __attribute__((ext_vector_type(8)));
typedef float f32x4 __attribute__((ext_vector_type(4)));
typedef unsigned short u16x8 __attribute__((ext_vector_type(8)));

constexpr int T = 8192, H = 2048, HS = 4096, P = 1024, E = 8;

// ---- d_out layout (floats): final [T*H] | router_logits [T*E] | aux_loss [1]
constexpr size_t LOGITS_OFF = (size_t)T * H;
constexpr size_t AUX_OFF    = LOGITS_OFF + (size_t)T * E;

// ---- workspace layout (bytes) — aliased buffers keep total ~225 MiB
// BIG0: x16 [T*H f16]   (dead after G1)  -> act  [T*2*P f16] (written G3)
// BIG1: c1  [T*HS f16]  (dead after G2)  -> slot [T*2*H f16] (written G4)
constexpr size_t OFF_SGW  = 0;
constexpr size_t OFF_SDW  = OFF_SGW  + (size_t)HS * H * 2;
constexpr size_t OFF_GW   = OFF_SDW  + (size_t)H * HS * 2;
constexpr size_t OFF_DW   = OFF_GW   + (size_t)E * P * H * 2;
constexpr size_t OFF_BIG0 = OFF_DW   + (size_t)E * H * P * 2;
constexpr size_t OFF_BIG1 = OFF_BIG0 + (size_t)T * H * 2;      // == T*2*P*2
constexpr size_t OFF_H1   = OFF_BIG1 + (size_t)T * HS * 2;     // == T*2*H*2
constexpr size_t OFF_GALL = OFF_H1   + (size_t)T * H * 2;
constexpr size_t OFF_CNT  = OFF_GALL + (size_t)T * E * 4;
constexpr size_t OFF_IMP  = OFF_CNT  + 256;
constexpr size_t OFF_OFFS = OFF_IMP  + 256;
constexpr size_t OFF_SEL  = OFF_OFFS + 256;
constexpr size_t OFF_SELW = OFF_SEL  + (size_t)T * 2 * 4;
constexpr size_t OFF_POS  = OFF_SELW + (size_t)T * 2 * 4;
constexpr size_t OFF_AID  = OFF_POS  + (size_t)T * 2 * 4;
constexpr size_t OFF_TOK  = OFF_AID  + (size_t)T * 2 * 4;
constexpr size_t OFF_WOF  = OFF_TOK  + (size_t)T * 2 * 4;

__device__ __forceinline__ unsigned short f2h(float f) {
  return __builtin_bit_cast(unsigned short, (_Float16)f);
}
__device__ __forceinline__ float h2f(unsigned short u) {
  return (float)__builtin_bit_cast(_Float16, u);
}
__device__ __forceinline__ void gload16(const void* g, void* l) {
  __builtin_amdgcn_global_load_lds((__attribute__((address_space(1))) void*)g,
                                   (__attribute__((address_space(3))) void*)l, 16, 0, 0);
}

// -------------------- fused weight convert (+ zero of cnts/imp) --------------------
__global__ void cvt4_kernel(const float* __restrict__ s0, const float* __restrict__ s1,
                            const float* __restrict__ s2, const float* __restrict__ s3,
                            unsigned short* __restrict__ d,
                            int* __restrict__ counts, float* __restrict__ imp) {
  if (blockIdx.x == 0 && threadIdx.x < E) { counts[threadIdx.x] = 0; imp[threadIdx.x] = 0.f; }
  const int i = blockIdx.x * 256 + threadIdx.x;   // float4 index, [0, 12M)
  constexpr int N0 = (HS * H) / 4;
  constexpr int N1 = N0 + (H * HS) / 4;
  constexpr int N2 = N1 + (E * P * H) / 4;
  float4 v;
  if (i < N0)      v = ((const float4*)s0)[i];
  else if (i < N1) v = ((const float4*)s1)[i - N0];
  else if (i < N2) v = ((const float4*)s2)[i - N1];
  else             v = ((const float4*)s3)[i - N2];
  ushort4 o;
  o.x = f2h(v.x); o.y = f2h(v.y); o.z = f2h(v.z); o.w = f2h(v.w);
  ((ushort4*)d)[i] = o;
}

// -------------------- router (rw staged in LDS; also emits x16) --------------------
__global__ void router_kernel(const float* __restrict__ x, const float* __restrict__ rw,
                              float* __restrict__ logits, int* __restrict__ counts,
                              float* __restrict__ impg, int* __restrict__ sel,
                              float* __restrict__ selw, int* __restrict__ posA,
                              unsigned short* __restrict__ x16) {
  __shared__ float sRW[E * H];        // 64 KiB: whole router weight staged once
  __shared__ float sImp[E];
  __shared__ int sCnt[E], sBase[E];
  __shared__ int sE[16][2], sS[16][2];
  const int tid = threadIdx.x, lane = tid & 63, wid = tid >> 6;
  if (tid < E) { sImp[tid] = 0.f; sCnt[tid] = 0; }
#pragma unroll
  for (int i = 0; i < (E * H / 4) / 256; ++i)
    ((float4*)sRW)[i * 256 + tid] = ((const float4*)rw)[i * 256 + tid];
  __syncthreads();

  for (int i = 0; i < 4; ++i) {
    const int ti = wid * 4 + i;
    const int t = blockIdx.x * 16 + ti;
    float p[E];
#pragma unroll
    for (int e = 0; e < E; ++e) p[e] = 0.f;
    const float4* xr = (const float4*)(x + (size_t)t * H);
#pragma unroll
    for (int q = 0; q < 8; ++q) {
      float4 xv = xr[q * 64 + lane];
      ushort4 xo;
      xo.x = f2h(xv.x); xo.y = f2h(xv.y); xo.z = f2h(xv.z); xo.w = f2h(xv.w);
      ((ushort4*)(x16 + (size_t)t * H))[q * 64 + lane] = xo;
#pragma unroll
      for (int e = 0; e < E; ++e) {
        float4 wv = ((const float4*)sRW)[e * 512 + q * 64 + lane];
        p[e] += xv.x * wv.x + xv.y * wv.y + xv.z * wv.z + xv.w * wv.w;
      }
    }
#pragma unroll
    for (int e = 0; e < E; ++e)
#pragma unroll
      for (int o = 32; o; o >>= 1) p[e] += __shfl_xor(p[e], o);

    if (lane == 0) {
      float mx = p[0];
#pragma unroll
      for (int e = 1; e < E; ++e) mx = fmaxf(mx, p[e]);
      float pe[E], s = 0.f;
#pragma unroll
      for (int e = 0; e < E; ++e) { pe[e] = expf(p[e] - mx); s += pe[e]; }
      float inv = 1.f / s;
      int i1 = 0; float b1 = pe[0];
#pragma unroll
      for (int e = 1; e < E; ++e) if (pe[e] > b1) { b1 = pe[e]; i1 = e; }
      int i2 = -1; float b2 = -1.f;
#pragma unroll
      for (int e = 0; e < E; ++e) if (e != i1 && pe[e] > b2) { b2 = pe[e]; i2 = e; }
#pragma unroll
      for (int e = 0; e < E; ++e) logits[(size_t)t * E + e] = p[e];
#pragma unroll
      for (int e = 0; e < E; ++e) atomicAdd(&sImp[e], pe[e] * inv);
      int s1 = atomicAdd(&sCnt[i1], 1);
      int s2 = atomicAdd(&sCnt[i2], 1);
      sel[t * 2] = i1; sel[t * 2 + 1] = i2;
      selw[t * 2] = b1 * inv; selw[t * 2 + 1] = b2 * inv;
      sE[ti][0] = i1; sE[ti][1] = i2; sS[ti][0] = s1; sS[ti][1] = s2;
    }
  }
  __syncthreads();
  if (tid < E) {
    sBase[tid] = atomicAdd(&counts[tid], sCnt[tid]);
    atomicAdd(&impg[tid], sImp[tid]);
  }
  __syncthreads();
  if (lane == 0) {
    for (int i = 0; i < 4; ++i) {
      int ti = wid * 4 + i, t = blockIdx.x * 16 + ti;
      posA[t * 2]     = sBase[sE[ti][0]] + sS[ti][0];
      posA[t * 2 + 1] = sBase[sE[ti][1]] + sS[ti][1];
    }
  }
}

// -------------------- fill (+ fused scan/aux): assignment-id maps --------------------
__global__ void fill_kernel(const int* __restrict__ sel, const float* __restrict__ selw,
                            const int* __restrict__ posA, const int* __restrict__ counts,
                            const float* __restrict__ imp,
                            int* __restrict__ offs, float* __restrict__ aux_out,
                            int* __restrict__ tok_of, float* __restrict__ w_of,
                            int* __restrict__ aid_of) {
  int c[E];
#pragma unroll
  for (int e = 0; e < E; ++e) c[e] = counts[e];
  int pre[E + 1];
  pre[0] = 0;
#pragma unroll
  for (int e = 0; e < E; ++e) pre[e + 1] = pre[e] + c[e];

  const int idx = blockIdx.x * 256 + threadIdx.x;  // 0 .. T*2
  if (blockIdx.x == 0 && threadIdx.x == 0) {
#pragma unroll
    for (int e = 0; e <= E; ++e) offs[e] = pre[e];
    float simp = 0.f, sld = (float)pre[E];
#pragma unroll
    for (int e = 0; e < E; ++e) simp += imp[e];
    float aux = 0.f;
#pragma unroll
    for (int e = 0; e < E; ++e)
      aux += (imp[e] / (simp + 1e-9f)) * ((float)c[e] / (sld + 1e-9f));
    aux_out[0] = (float)E * aux;
  }
  if (idx >= T * 2) return;
  int t = idx >> 1;
  int e = sel[idx];
  int aid = pre[e] + posA[idx];
  tok_of[aid] = t;
  w_of[aid] = selw[idx];
  aid_of[idx] = aid;
}

// -------------------- g kernel: g_all[t,e] = sigmoid(h1 . pg_w[e]) --------------------
__global__ void g_kernel(const unsigned short* __restrict__ h1, const float* __restrict__ pgw,
                         float* __restrict__ g_all) {
  const int lane = threadIdx.x & 63, wid = threadIdx.x >> 6;
  const int t = blockIdx.x * 4 + wid;
  float p[E];
#pragma unroll
  for (int e = 0; e < E; ++e) p[e] = 0.f;
#pragma unroll
  for (int i = 0; i < 4; ++i) {
    const int h = (i * 64 + lane) * 8;
    u16x8 hv = *(const u16x8*)(h1 + (size_t)t * H + h);
    float hf[8];
#pragma unroll
    for (int j = 0; j < 8; ++j) hf[j] = h2f(hv[j]);
#pragma unroll
    for (int e = 0; e < E; ++e) {
      const float4* wp = (const float4*)(pgw + (size_t)e * H + h);
      float4 w0 = wp[0], w1 = wp[1];
      p[e] += hf[0] * w0.x + hf[1] * w0.y + hf[2] * w0.z + hf[3] * w0.w +
              hf[4] * w1.x + hf[5] * w1.y + hf[6] * w1.z + hf[7] * w1.w;
    }
  }
#pragma unroll
  for (int e = 0; e < E; ++e)
#pragma unroll
    for (int o = 32; o; o >>= 1) p[e] += __shfl_xor(p[e], o);
  if (lane == 0) {
#pragma unroll
    for (int e = 0; e < E; ++e) g_all[(size_t)t * E + e] = 1.f / (1.f + expf(-p[e]));
  }
}

// -------------------- the GEMM: C[M,N] = A[M,K] . B[N,K]^T (f16 in, MFMA, f16 out)
// Proven core (128x128 tile, 4 waves, BK=64, T2 swizzle, global_load_lds w=16).
// r9: XCD-slab swizzle for MODE<=1 (xcd = wg&7 preserved, contiguous bm slabs).
// r11: MODE>=2 uses a 1-D grid with EXPERT->XCD PINNING: e = blockIdx.x & 7
// lands all of expert e's blocks on XCD e, so each XCD-L2 holds ONE expert's
// B (4 MB, fits) instead of all eight (32 MB) — removes the L3-latency B-stage
// misses that made G3/G4 2x slower per iteration than G1/G2.
// MODE 0: plain rows, relu; MODE 1: plain; MODE 2: gathered rows, relu(g*v);
// MODE 3: rows=aid, w*v.
template <int MODE>
__global__ __launch_bounds__(256, 4) void gemm_bt(
    const unsigned short* __restrict__ A, const unsigned short* __restrict__ B,
    unsigned short* __restrict__ Cout, const int* __restrict__ tok_of,
    const float* __restrict__ g_all, const float* __restrict__ w_of,
    const int* __restrict__ offs, int N, int K) {
  __shared__ alignas(128) char sA[128 * 64 * 2];
  __shared__ alignas(128) char sB[128 * 64 * 2];
  const int tid = threadIdx.x, lane = tid & 63, wid = tid >> 6;
  const int wr = wid >> 1, wc = wid & 1;

  int bm, bn;
  int rowStart = 0, cnt = 1 << 30, e = 0;
  const unsigned short* Bp = B;
  if (MODE <= 1) {
    bm = blockIdx.x; bn = blockIdx.y;
    // XCD-slab swizzle: valid when gridDim.x == 64 (G1 & G2: T/128 = 64).
    if (gridDim.x == 64) {
      const int wg = blockIdx.y * 64 + blockIdx.x;
      const int xcd = wg & 7;
      const int idx = wg >> 3;            // 0 .. nwg/8-1
      bm = xcd * 8 + (idx & 7);           // contiguous 8-panel A-slab per XCD
      bn = idx >> 3;                      // sweep N within the slab
    }
  } else {
    // 1-D grid = 64 * nbn * 8. Expert pinned to XCD: e = wg & 7.
    const int nbn = N >> 7;               // 8 (G3) or 16 (G4), power of two
    const int nbsh = __builtin_ctz(nbn);
    e = blockIdx.x & 7;
    const int idx = blockIdx.x >> 3;      // per-expert work item
    bn = idx & (nbn - 1);                 // bn fastest: concurrent blocks share A-rows
    bm = idx >> nbsh;
    rowStart = offs[e];
    cnt = offs[e + 1] - rowStart;
    if (bm * 128 >= cnt) return;          // uniform per block: barrier-safe
    Bp = B + (size_t)e * N * K;
  }

  // staging pointers: chunk ci = wid*4+it covers tile bytes [ci*1024, +1024), lane -> +lane*16
  const char* aSrc[4];
  const char* bSrc[4];
  char* dA[4];
  char* dB[4];
#pragma unroll
  for (int it = 0; it < 4; ++it) {
    const int ci = wid * 4 + it;
    const int o = ci * 1024 + lane * 16;
    const int row = o >> 7;                        // 128 B per row (BK=64 f16)
    const int cbs = (o & 127) ^ ((row & 7) << 4);  // pre-swizzled source column
    dA[it] = sA + ci * 1024;
    dB[it] = sB + ci * 1024;
    long arow;
    if (MODE <= 1) {
      arow = (long)(bm * 128 + row);
    } else if (MODE == 2) {
      int grow = bm * 128 + row;
      arow = (grow < cnt) ? (long)tok_of[rowStart + grow] : 0L;
    } else {
      int grow = bm * 128 + row;
      arow = (grow < cnt) ? (long)(rowStart + grow) : (long)rowStart;
    }
    aSrc[it] = (const char*)A + arow * (long)K * 2 + cbs;
    bSrc[it] = (const char*)Bp + (long)(bn * 128 + row) * (long)K * 2 + cbs;
  }

  f32x4 acc[4][4];
#pragma unroll
  for (int a_ = 0; a_ < 4; ++a_)
#pragma unroll
    for (int b_ = 0; b_ < 4; ++b_) acc[a_][b_] = (f32x4){0.f, 0.f, 0.f, 0.f};

  for (int k0 = 0; k0 < K; k0 += 64) {
#pragma unroll
    for (int it = 0; it < 4; ++it) {
      gload16(aSrc[it] + (size_t)k0 * 2, dA[it]);
      gload16(bSrc[it] + (size_t)k0 * 2, dB[it]);
    }
    __syncthreads();
#pragma unroll
    for (int kk = 0; kk < 2; ++kk) {
      f16x8 af[4], bfr[4];
      const int c0 = kk * 64 + (lane >> 4) * 16;
#pragma unroll
      for (int mt = 0; mt < 4; ++mt) {
        const int r = wr * 64 + mt * 16 + (lane & 15);
        af[mt] = *(const f16x8*)(sA + r * 128 + (c0 ^ ((r & 7) << 4)));
      }
#pragma unroll
      for (int nt = 0; nt < 4; ++nt) {
        const int r = wc * 64 + nt * 16 + (lane & 15);
        bfr[nt] = *(const f16x8*)(sB + r * 128 + (c0 ^ ((r & 7) << 4)));
      }
#pragma unroll
      for (int mt = 0; mt < 4; ++mt)
#pragma unroll
        for (int nt = 0; nt < 4; ++nt)
          acc[mt][nt] = __builtin_amdgcn_mfma_f32_16x16x32_f16(af[mt], bfr[nt], acc[mt][nt], 0, 0, 0);
    }
    __syncthreads();
  }

  // epilogue: C row = bm*128 + wr*64 + mt*16 + (lane>>4)*4 + j ; col = bn*128 + wc*64 + nt*16 + (lane&15)
  const int colBase = bn * 128 + wc * 64 + (lane & 15);
#pragma unroll
  for (int mt = 0; mt < 4; ++mt) {
#pragma unroll
    for (int j = 0; j < 4; ++j) {
      const int rloc = wr * 64 + mt * 16 + (lane >> 4) * 4 + j;
      const int grow = bm * 128 + rloc;
      if (MODE <= 1) {
        const size_t base = (size_t)grow * N;
#pragma unroll
        for (int nt = 0; nt < 4; ++nt) {
          float v = acc[mt][nt][j];
          if (MODE == 0) v = fmaxf(v, 0.f);
          Cout[base + colBase + nt * 16] = f2h(v);
        }
      } else if (MODE == 2) {
        if (grow < cnt) {
          const int aid = rowStart + grow;
          const float g = g_all[(size_t)tok_of[aid] * E + e];
          const size_t base = (size_t)aid * N;
#pragma unroll
          for (int nt = 0; nt < 4; ++nt) {
            float v = fmaxf(g * acc[mt][nt][j], 0.f);
            Cout[base + colBase + nt * 16] = f2h(v);
          }
        }
      } else {
        if (grow < cnt) {
          const int aid = rowStart + grow;
          const float w = w_of[aid];
          const size_t base = (size_t)aid * N;
#pragma unroll
          for (int nt = 0; nt < 4; ++nt)
            Cout[base + colBase + nt * 16] = f2h(w * acc[mt][nt][j]);
        }
      }
    }
  }
}

// -------------------- combine: final[t,:] = slot[aid0] + slot[aid1] --------------------
__global__ void combine_kernel(const unsigned short* __restrict__ slot,
                               const int* __restrict__ aid_of, float* __restrict__ out) {
  const int idx = blockIdx.x * 256 + threadIdx.x;
  const int t = idx >> 8;
  const int c8 = (idx & 255) * 8;
  const int a0 = aid_of[t * 2], a1 = aid_of[t * 2 + 1];
  u16x8 v0 = *(const u16x8*)(slot + (size_t)a0 * H + c8);
  u16x8 v1 = *(const u16x8*)(slot + (size_t)a1 * H + c8);
  float4 f0, f1;
  f0.x = h2f(v0[0]) + h2f(v1[0]); f0.y = h2f(v0[1]) + h2f(v1[1]);
  f0.z = h2f(v0[2]) + h2f(v1[2]); f0.w = h2f(v0[3]) + h2f(v1[3]);
  f1.x = h2f(v0[4]) + h2f(v1[4]); f1.y = h2f(v0[5]) + h2f(v1[5]);
  f1.z = h2f(v0[6]) + h2f(v1[6]); f1.w = h2f(v0[7]) + h2f(v1[7]);
  float4* op = (float4*)(out + (size_t)t * H + c8);
  op[0] = f0; op[1] = f1;
}

// -------------------- launch --------------------
extern "C" void kernel_launch(void* const* d_in, const int* in_sizes, int n_in,
                              void* d_out, int out_size, void* d_ws, size_t ws_size,
                              hipStream_t stream) {
  const float* x   = (const float*)d_in[0];
  const float* rw  = (const float*)d_in[1];
  const float* sgw = (const float*)d_in[2];
  const float* sdw = (const float*)d_in[3];
  const float* pgw = (const float*)d_in[4];
  const float* gw  = (const float*)d_in[5];
  const float* dw  = (const float*)d_in[6];
  float* out = (float*)d_out;
  char* wsb = (char*)d_ws;

  unsigned short* sgw16 = (unsigned short*)(wsb + OFF_SGW);
  unsigned short* sdw16 = (unsigned short*)(wsb + OFF_SDW);
  unsigned short* gw16  = (unsigned short*)(wsb + OFF_GW);
  unsigned short* dw16  = (unsigned short*)(wsb + OFF_DW);
  unsigned short* x16   = (unsigned short*)(wsb + OFF_BIG0);  // alias: act
  unsigned short* act   = (unsigned short*)(wsb + OFF_BIG0);
  unsigned short* c1    = (unsigned short*)(wsb + OFF_BIG1);  // alias: slot
  unsigned short* slot  = (unsigned short*)(wsb + OFF_BIG1);
  unsigned short* h1    = (unsigned short*)(wsb + OFF_H1);
  float* gall  = (float*)(wsb + OFF_GALL);
  int*   cnts  = (int*)(wsb + OFF_CNT);
  float* imp   = (float*)(wsb + OFF_IMP);
  int*   offs  = (int*)(wsb + OFF_OFFS);
  int*   sel   = (int*)(wsb + OFF_SEL);
  float* selw  = (float*)(wsb + OFF_SELW);
  int*   posA  = (int*)(wsb + OFF_POS);
  int*   aidof = (int*)(wsb + OFF_AID);
  int*   tokof = (int*)(wsb + OFF_TOK);
  float* wof   = (float*)(wsb + OFF_WOF);

  // fused weight converts (+ zero cnts/imp in block 0): 12M float4 total
  cvt4_kernel<<<(HS * H + H * HS + E * P * H + E * H * P) / 4 / 256, 256, 0, stream>>>(
      sgw, sdw, gw, dw, sgw16, cnts, imp);

  // router also produces x16 (rw staged in LDS)
  router_kernel<<<T / 16, 256, 0, stream>>>(x, rw, out + LOGITS_OFF, cnts, imp, sel, selw, posA, x16);

  // fill (+ fused offs/aux computation)
  fill_kernel<<<(T * 2) / 256, 256, 0, stream>>>(sel, selw, posA, cnts, imp, offs, out + AUX_OFF,
                                                 tokof, wof, aidof);

  // G1: [T,HS] = relu(x16 . sgw^T), K=H
  gemm_bt<0><<<dim3(T / 128, HS / 128), 256, 0, stream>>>(x16, sgw16, c1, nullptr, nullptr, nullptr, nullptr, HS, H);
  // G2: h1[T,H] = c1 . sdw^T, K=HS
  gemm_bt<1><<<dim3(T / 128, H / 128), 256, 0, stream>>>(c1, sdw16, h1, nullptr, nullptr, nullptr, nullptr, H, HS);
  // g
  g_kernel<<<T / 4, 256, 0, stream>>>(h1, pgw, gall);
  // G3: act[aid,P] = relu(g * (h1_gathered . gw[e]^T)), K=H — expert->XCD pinned 1-D grid
  gemm_bt<2><<<64 * (P / 128) * E, 256, 0, stream>>>(h1, gw16, act, tokof, gall, nullptr, offs, P, H);
  // G4: slot[aid,H] = w * (act . dw[e]^T), K=P — expert->XCD pinned 1-D grid
  gemm_bt<3><<<64 * (H / 128) * E, 256, 0, stream>>>(act, dw16, slot, tokof, nullptr, wof, offs, H, P);

  combine_kernel<<<(T * 256) / 256, 256, 0, stream>>>(slot, aidof, out);
}